// Round 1
// 638.776 us; speedup vs baseline: 1.1517x; 1.1517x over previous
//
#include <hip/hip_runtime.h>

// Problem constants (B=2, H=16, L=2048, D=64 — fixed by the reference setup).
#define BH   32
#define LSEQ 2048
#define DDIM 64
#define ERRC 1e-12f

typedef __attribute__((ext_vector_type(8))) short  bf16x8;
typedef __attribute__((ext_vector_type(4))) float  floatx4;
typedef __attribute__((ext_vector_type(4))) unsigned short ushort4v;

// float -> bf16 round-to-nearest-even (inputs are finite, no NaN handling needed)
__device__ __forceinline__ unsigned short f2bf(float f) {
    unsigned u = __float_as_uint(f);
    u = u + 0x7FFFu + ((u >> 16) & 1u);
    return (unsigned short)(u >> 16);
}

__device__ __forceinline__ bf16x8 pack8s(const float* __restrict__ p, float w) {
    const floatx4* pv = (const floatx4*)p;
    floatx4 x = pv[0], y = pv[1];
    bf16x8 r;
    r[0] = (short)f2bf(x[0] * w); r[1] = (short)f2bf(x[1] * w);
    r[2] = (short)f2bf(x[2] * w); r[3] = (short)f2bf(x[3] * w);
    r[4] = (short)f2bf(y[0] * w); r[5] = (short)f2bf(y[1] * w);
    r[6] = (short)f2bf(y[2] * w); r[7] = (short)f2bf(y[3] * w);
    return r;
}

// Prep: ks = bf16(k * sqrt(src+err)), kd = bf16(k * sqrt(dest+err)).
// Matches the reference's (k*s) @ (k*d)^T structure; removes per-tile scaling
// from the hot loop. 4,194,304 elements, 4 per thread.
__global__ __launch_bounds__(256) void prep_scaled(const float* __restrict__ k,
                                                   const float* __restrict__ src,
                                                   const float* __restrict__ dest,
                                                   unsigned short* __restrict__ ks,
                                                   unsigned short* __restrict__ kd) {
    int idx4 = blockIdx.x * 256 + threadIdx.x;
    int row  = idx4 >> 4;                     // 16 float4 per 64-wide row
    float s = sqrtf(src[row] + ERRC);
    float d = sqrtf(dest[row] + ERRC);
    floatx4 v = ((const floatx4*)k)[idx4];
    ushort4v os, od;
#pragma unroll
    for (int r = 0; r < 4; ++r) { os[r] = f2bf(v[r] * s); od[r] = f2bf(v[r] * d); }
    ((ushort4v*)ks)[idx4] = os;
    ((ushort4v*)kd)[idx4] = od;
}

// Load one 16-row fragment (rows indexed by l16, k-dim split q*8..q*8+7 / +32).
// Identical layout serves both the A operand (kd, j rows) and B operand (ks, i rows):
// A[m=lane&15][k=q*8+t], B[k=q*8+t][n=lane&15].
template<bool RAW>
__device__ __forceinline__ void load_row(const void* __restrict__ kp, long base, int row,
                                         int q, const float* __restrict__ w, int bhL,
                                         bf16x8& lo, bf16x8& hi) {
    if (RAW) {
        const float* p = (const float*)kp + base + (long)row * DDIM + q * 8;
        float s = sqrtf(w[bhL + row] + ERRC);
        lo = pack8s(p, s);
        hi = pack8s(p + 32, s);
    } else {
        const unsigned short* p = (const unsigned short*)kp + base + (long)row * DDIM + q * 8;
        lo = *(const bf16x8*)p;
        hi = *(const bf16x8*)(p + 32);
    }
}

// Scan + store for one 16(j)x16(i) tile. Swapped-operand C-layout: lane (q,l16)
// holds rows j0+q*4+r (r=0..3) of column i0+l16 — j is IN-LANE and consecutive.
// Below-diagonal tiles only feed the carry: sum via 2-step butterfly, store zeros.
__device__ __forceinline__ void scan_store(float t[4], int j0, int i0, int q, int l16,
                                           float& carry, float* __restrict__ op) {
    if (j0 + 16 <= i0) {                      // fully masked tile: need only the sum
        float g = (t[0] + t[1]) + (t[2] + t[3]);
        g += __shfl_xor(g, 16, 64);
        g += __shfl_xor(g, 32, 64);
        carry += g;
        floatx4 z = {0.f, 0.f, 0.f, 0.f};
        *(floatx4*)op = z;
    } else {
        // in-lane inclusive prefix over the lane's 4 consecutive j
        t[1] += t[0]; t[2] += t[1]; t[3] += t[2];
        float g = t[3];                        // this q-group's sum
        // inclusive Hillis-Steele over q (lane stride 16)
        float u1 = __shfl_up(g, 16, 64);
        float h = g + ((q >= 1) ? u1 : 0.f);
        float u2 = __shfl_up(h, 32, 64);
        h += ((q >= 2) ? u2 : 0.f);
        float bse = (h - g) + carry;           // exclusive cross-q prefix + running carry
        carry += __shfl(h, 48 + l16, 64);      // tile total lives at q==3
        floatx4 o;
        if (j0 == i0) {                        // the single mixed (diagonal) tile
#pragma unroll
            for (int r = 0; r < 4; ++r)
                o[r] = ((q * 4 + r) >= l16) ? (t[r] + bse) : 0.f;
        } else {                               // fully above diagonal
#pragma unroll
            for (int r = 0; r < 4; ++r)
                o[r] = t[r] + bse;
        }
        *(floatx4*)op = o;                     // one dwordx4 per lane (cached, L2-coalesced)
    }
}

// One wave = one 16-column i-tile; streams 64 pairs of 16-row j-tiles.
// Swapped MFMA: D = kd_tile(j rows) . ks_rows(i)^T -> D[m=j][n=i],
// C/D: col(l16)=i, row(q*4+r)=j.
template<bool RAW>
__global__ __launch_bounds__(256) void mha_fused2(const void* __restrict__ ka,   // kd (or raw k)
                                                  const void* __restrict__ kb,   // ks (or raw k)
                                                  const float* __restrict__ src,
                                                  const float* __restrict__ dest,
                                                  float* __restrict__ out) {
    const int tid  = threadIdx.x;
    const int wave = tid >> 6;
    const int lane = tid & 63;
    const int q    = lane >> 4;
    const int l16  = lane & 15;
    // bh in low bits: same-bh blocks are 32 apart -> same XCD under mod-8 dispatch.
    const int bh = blockIdx.x & 31;
    const int ib = blockIdx.x >> 5;           // 0..31
    const int i0 = (ib * 4 + wave) * 16;      // this wave's 16-column (i) tile
    const int bhL = bh * LSEQ;
    const long base = (long)bh * LSEQ * DDIM;

    // B operand: ks row i0+l16, held for the whole kernel
    bf16x8 blo, bhi;
    load_row<RAW>(kb, base, i0 + l16, q, src, bhL, blo, bhi);

    float carry = 0.f;                        // running row sum (per i = l16, same across q)
    const float c23 = 2.0f / 3.0f;

    // prefetch j-tiles 0 and 1
    bf16x8 aAlo, aAhi, aBlo, aBhi;
    load_row<RAW>(ka, base, l16,      q, dest, bhL, aAlo, aAhi);
    load_row<RAW>(ka, base, 16 + l16, q, dest, bhL, aBlo, aBhi);

    float* orow = out + (long)(bhL + i0 + l16) * LSEQ + q * 4;

    for (int jp = 0; jp < 64; ++jp) {
        const int j0A = jp << 5;
        const int j0B = j0A + 16;

        // prefetch next tile pair (clamped redundant load on last iter)
        bf16x8 nAlo, nAhi, nBlo, nBhi;
        const int jn = (jp < 63) ? (jp + 1) << 5 : j0A;
        load_row<RAW>(ka, base, jn + l16,      q, dest, bhL, nAlo, nAhi);
        load_row<RAW>(ka, base, jn + 16 + l16, q, dest, bhL, nBlo, nBhi);

        floatx4 accA = {0.f, 0.f, 0.f, 0.f};
        floatx4 accB = {0.f, 0.f, 0.f, 0.f};
        accA = __builtin_amdgcn_mfma_f32_16x16x32_bf16(aAlo, blo, accA, 0, 0, 0);
        accB = __builtin_amdgcn_mfma_f32_16x16x32_bf16(aBlo, blo, accB, 0, 0, 0);
        accA = __builtin_amdgcn_mfma_f32_16x16x32_bf16(aAhi, bhi, accA, 0, 0, 0);
        accB = __builtin_amdgcn_mfma_f32_16x16x32_bf16(aBhi, bhi, accB, 0, 0, 0);

        // a3 = exp2(log2(relu(a1)+err) * 2/3), two independent tiles for ILP
        float tA[4], tB[4];
#pragma unroll
        for (int r = 0; r < 4; ++r) {
            float vA = fmaxf(accA[r], 0.f) + ERRC;
            tA[r] = exp2f(c23 * __log2f(vA));
            float vB = fmaxf(accB[r], 0.f) + ERRC;
            tB[r] = exp2f(c23 * __log2f(vB));
        }

        scan_store(tA, j0A, i0, q, l16, carry, orow);
        scan_store(tB, j0B, i0, q, l16, carry, orow + 16);

        orow += 32;
        aAlo = nAlo; aAhi = nAhi; aBlo = nBlo; aBhi = nBhi;
    }
}

extern "C" void kernel_launch(void* const* d_in, const int* in_sizes, int n_in,
                              void* d_out, int out_size, void* d_ws, size_t ws_size,
                              hipStream_t stream) {
    const float* k    = (const float*)d_in[0];
    const float* src  = (const float*)d_in[1];
    const float* dest = (const float*)d_in[2];
    float* out = (float*)d_out;

    const size_t half = (size_t)BH * LSEQ * DDIM * sizeof(unsigned short); // 8 MiB
    if (ws_size >= 2 * half) {
        unsigned short* ks = (unsigned short*)d_ws;
        unsigned short* kd = (unsigned short*)((char*)d_ws + half);
        prep_scaled<<<dim3(4096), dim3(256), 0, stream>>>(k, src, dest, ks, kd);
        mha_fused2<false><<<dim3(1024), dim3(256), 0, stream>>>(kd, ks, src, dest, out);
    } else {
        mha_fused2<true><<<dim3(1024), dim3(256), 0, stream>>>(k, k, src, dest, out);
    }
}